// Round 2
// baseline (6886.687 us; speedup 1.0000x reference)
//
#include <hip/hip_runtime.h>
#include <math.h>

#define DD 768
#define HH 384
#define LL 32
#define BSZ 4096

static __device__ __forceinline__ double gelud(double x) {
    return 0.5 * x * (1.0 + erf(x * 0.70710678118654752440));
}

// ---------------------------------------------------------------------------
// Per-row mean / rstd over 768 floats, fp64 accumulation. One wave per row.
// ---------------------------------------------------------------------------
__global__ __launch_bounds__(256) void row_stats_k(const float* __restrict__ X,
                                                   double* __restrict__ mean,
                                                   double* __restrict__ rstd,
                                                   int nrows) {
    int w = (int)((blockIdx.x * blockDim.x + threadIdx.x) >> 6);
    int lane = threadIdx.x & 63;
    if (w >= nrows) return;
    const float* row = X + (size_t)w * DD;
    double s = 0., q = 0.;
#pragma unroll
    for (int i = 0; i < 3; i++) {
        float4 v = *(const float4*)(row + ((lane + (i << 6)) << 2));
        double a = v.x, b = v.y, c = v.z, d = v.w;
        s += a + b + c + d;
        q += a * a + b * b + c * c + d * d;
    }
#pragma unroll
    for (int m = 1; m < 64; m <<= 1) {
        s += __shfl_xor(s, m, 64);
        q += __shfl_xor(q, m, 64);
    }
    if (lane == 0) {
        double mu = s * (1.0 / 768.0);
        double var = q * (1.0 / 768.0) - mu * mu;
        mean[w] = mu;
        rstd[w] = rsqrt(var + 1e-5);
    }
}

// ---------------------------------------------------------------------------
// Out = gelu( LN(A) @ W + bias ), fp64 accumulation, Out stored double.
// 128x64 tile, 256 threads, 8x4 per thread, k-tile 16.
// ---------------------------------------------------------------------------
__global__ __launch_bounds__(256) void gemm_ln_gelu_k(
    const float* __restrict__ A, const double* __restrict__ mean,
    const double* __restrict__ rstd, const float* __restrict__ lng,
    const float* __restrict__ lnb, const float* __restrict__ W,
    const float* __restrict__ bias, double* __restrict__ Out, int Ncols) {
    __shared__ double As[16][132];
    __shared__ float Bs[16][68];
    const int tid = threadIdx.x;
    const int m0 = blockIdx.x << 7;
    const int n0 = blockIdx.y << 6;
    const int ty = tid >> 4, tx = tid & 15;
    const int ks = tid & 15, ms = tid >> 4;

    double smu[8], srs[8];
#pragma unroll
    for (int i = 0; i < 8; i++) {
        int m = ms + (i << 4);
        smu[i] = mean[m0 + m];
        srs[i] = rstd[m0 + m];
    }
    double acc[8][4] = {};
    const float* Ab = A + (size_t)m0 * DD;

    for (int kb = 0; kb < DD; kb += 16) {
        double gk = (double)lng[kb + ks], bk = (double)lnb[kb + ks];
#pragma unroll
        for (int i = 0; i < 8; i++) {
            int m = ms + (i << 4);
            double v = (double)Ab[(size_t)m * DD + kb + ks];
            As[ks][m] = (v - smu[i]) * srs[i] * gk + bk;
        }
        {
            int k = tid >> 4, n = (tid & 15) << 2;
            *(float4*)&Bs[k][n] = *(const float4*)&W[(size_t)(kb + k) * Ncols + n0 + n];
        }
        __syncthreads();
#pragma unroll
        for (int kk = 0; kk < 16; kk++) {
            double2 a01 = *(double2*)&As[kk][(ty << 3) + 0];
            double2 a23 = *(double2*)&As[kk][(ty << 3) + 2];
            double2 a45 = *(double2*)&As[kk][(ty << 3) + 4];
            double2 a67 = *(double2*)&As[kk][(ty << 3) + 6];
            float4 bf = *(float4*)&Bs[kk][tx << 2];
            double av[8] = {a01.x, a01.y, a23.x, a23.y, a45.x, a45.y, a67.x, a67.y};
            double bv[4] = {(double)bf.x, (double)bf.y, (double)bf.z, (double)bf.w};
#pragma unroll
            for (int r = 0; r < 8; r++)
#pragma unroll
                for (int c = 0; c < 4; c++) acc[r][c] = fma(av[r], bv[c], acc[r][c]);
        }
        __syncthreads();
    }

    double bb[4];
    {
        float4 t = *(const float4*)&bias[n0 + (tx << 2)];
        bb[0] = t.x; bb[1] = t.y; bb[2] = t.z; bb[3] = t.w;
    }
#pragma unroll
    for (int r = 0; r < 8; r++) {
        int m = m0 + (ty << 3) + r;
        double* dst = Out + (size_t)m * Ncols + n0 + (tx << 2);
        double2 o0, o1;
        o0.x = gelud(acc[r][0] + bb[0]);
        o0.y = gelud(acc[r][1] + bb[1]);
        o1.x = gelud(acc[r][2] + bb[2]);
        o1.y = gelud(acc[r][3] + bb[3]);
        *(double2*)dst = o0;
        *(double2*)(dst + 2) = o1;
    }
}

// ---------------------------------------------------------------------------
// Per-row: gate = tanh(v2 . qa2[batch]); fold LN(v2*gate) into s1, s2.
// All fp64. Also init logits row to gr_b2.
// ---------------------------------------------------------------------------
__global__ __launch_bounds__(256) void gate_stats_k(
    const double* __restrict__ V2, const double* __restrict__ qa2,
    double* __restrict__ s1, double* __restrict__ s2,
    double* __restrict__ logits, const float* __restrict__ b2,
    int rowbase, int nrows) {
    int r = (int)((blockIdx.x * blockDim.x + threadIdx.x) >> 6);
    int lane = threadIdx.x & 63;
    if (r >= nrows) return;
    const double* vr = V2 + (size_t)r * DD;
    const double* qr = qa2 + (size_t)((rowbase + r) >> 5) * DD;
    double dot = 0., s = 0., q = 0.;
#pragma unroll
    for (int i = 0; i < 3; i++) {
        int idx = (lane + (i << 6)) << 2;
        double2 a0 = *(const double2*)(vr + idx);
        double2 a1 = *(const double2*)(vr + idx + 2);
        double2 b0 = *(const double2*)(qr + idx);
        double2 b1 = *(const double2*)(qr + idx + 2);
        dot += a0.x * b0.x + a0.y * b0.y + a1.x * b1.x + a1.y * b1.y;
        s += a0.x + a0.y + a1.x + a1.y;
        q += a0.x * a0.x + a0.y * a0.y + a1.x * a1.x + a1.y * a1.y;
    }
#pragma unroll
    for (int m = 1; m < 64; m <<= 1) {
        dot += __shfl_xor(dot, m, 64);
        s += __shfl_xor(s, m, 64);
        q += __shfl_xor(q, m, 64);
    }
    double gate = tanh(dot);
    double mu = gate * (s * (1.0 / 768.0));
    double var = gate * gate * (q * (1.0 / 768.0)) - mu * mu;
    double rs = rsqrt(var + 1e-5);
    if (lane == 0) {
        s1[r] = gate * rs;
        s2[r] = mu * rs;
        logits[rowbase + r] = (double)b2[0];
    }
}

// ---------------------------------------------------------------------------
// t = gelu( (folded LN of v2*gate) @ W1 + b1 ); logits += t @ w2. fp64.
// 128x64 tile over (rows x 384). Partial reduce in-block, atomicAdd(double).
// ---------------------------------------------------------------------------
__global__ __launch_bounds__(256) void gemm_h_logits_k(
    const double* __restrict__ V2, const double* __restrict__ s1,
    const double* __restrict__ s2, const float* __restrict__ gg,
    const float* __restrict__ gb, const float* __restrict__ W1,
    const float* __restrict__ b1, const float* __restrict__ w2,
    double* __restrict__ logits) {
    __shared__ double As[16][132];
    __shared__ float Bs[16][68];
    __shared__ double red[128][17];
    const int tid = threadIdx.x;
    const int m0 = blockIdx.x << 7;
    const int n0 = blockIdx.y << 6;
    const int ty = tid >> 4, tx = tid & 15;
    const int ks = tid & 15, ms = tid >> 4;

    double ss1[8], ss2[8];
#pragma unroll
    for (int i = 0; i < 8; i++) {
        int m = ms + (i << 4);
        ss1[i] = s1[m0 + m];
        ss2[i] = s2[m0 + m];
    }
    double acc[8][4] = {};
    const double* Ab = V2 + (size_t)m0 * DD;

    for (int kb = 0; kb < DD; kb += 16) {
        double gk = (double)gg[kb + ks], bk = (double)gb[kb + ks];
#pragma unroll
        for (int i = 0; i < 8; i++) {
            int m = ms + (i << 4);
            double v = Ab[(size_t)m * DD + kb + ks];
            As[ks][m] = gk * (v * ss1[i] - ss2[i]) + bk;
        }
        {
            int k = tid >> 4, n = (tid & 15) << 2;
            *(float4*)&Bs[k][n] = *(const float4*)&W1[(size_t)(kb + k) * HH + n0 + n];
        }
        __syncthreads();
#pragma unroll
        for (int kk = 0; kk < 16; kk++) {
            double2 a01 = *(double2*)&As[kk][(ty << 3) + 0];
            double2 a23 = *(double2*)&As[kk][(ty << 3) + 2];
            double2 a45 = *(double2*)&As[kk][(ty << 3) + 4];
            double2 a67 = *(double2*)&As[kk][(ty << 3) + 6];
            float4 bf = *(float4*)&Bs[kk][tx << 2];
            double av[8] = {a01.x, a01.y, a23.x, a23.y, a45.x, a45.y, a67.x, a67.y};
            double bv[4] = {(double)bf.x, (double)bf.y, (double)bf.z, (double)bf.w};
#pragma unroll
            for (int r = 0; r < 8; r++)
#pragma unroll
                for (int c = 0; c < 4; c++) acc[r][c] = fma(av[r], bv[c], acc[r][c]);
        }
        __syncthreads();
    }

    double bb[4], ww[4];
    {
        float4 t = *(const float4*)&b1[n0 + (tx << 2)];
        bb[0] = t.x; bb[1] = t.y; bb[2] = t.z; bb[3] = t.w;
        float4 u = *(const float4*)&w2[n0 + (tx << 2)];
        ww[0] = u.x; ww[1] = u.y; ww[2] = u.z; ww[3] = u.w;
    }
#pragma unroll
    for (int r = 0; r < 8; r++) {
        double p = 0.;
#pragma unroll
        for (int c = 0; c < 4; c++) p += gelud(acc[r][c] + bb[c]) * ww[c];
        red[(ty << 3) + r][tx] = p;
    }
    __syncthreads();
    if (tid < 128) {
        double sum = 0.;
#pragma unroll
        for (int j = 0; j < 16; j++) sum += red[tid][j];
        atomicAdd(&logits[m0 + tid], sum);
    }
}

// ---------------------------------------------------------------------------
// Per-batch tail, all fp64: softmax -> gaussian conv5 -> softmax -> scan.
// Serial parts on lane 0 replicate reference order exactly.
// ---------------------------------------------------------------------------
__global__ __launch_bounds__(64) void finalize_k(const double* __restrict__ logits,
                                                 const float* __restrict__ sigma,
                                                 float* __restrict__ out) {
    int b = blockIdx.x;
    int l = threadIdx.x;
    __shared__ double lg[32], kp[32], gs[32], cs[33];
    __shared__ int sb[2];
    double x = 0.;
    if (l < 32) {
        x = logits[(b << 5) + l];
        lg[l] = x;
    }
    __syncthreads();
    double kern[5];
    {
        double inv = 1.0 / (double)sigma[0];
        double ssum = 0.;
#pragma unroll
        for (int j = 0; j < 5; j++) {
            double t = (double)(j - 2) * inv;
            kern[j] = exp(-0.5 * t * t);
            ssum += kern[j];
        }
#pragma unroll
        for (int j = 0; j < 5; j++) kern[j] /= ssum;
    }
    if (l < 32) {
        double mx = x;
#pragma unroll
        for (int m = 1; m < 32; m <<= 1) mx = fmax(mx, __shfl_xor(mx, m, 32));
        double e = exp(x - mx);
        double sum = e;
#pragma unroll
        for (int m = 1; m < 32; m <<= 1) sum += __shfl_xor(sum, m, 32);
        kp[l] = e / sum;
    }
    __syncthreads();
    if (l < 32) {
        double smv = 0.;
#pragma unroll
        for (int j = 0; j < 5; j++) {
            int t = l + j - 2;
            if (t >= 0 && t < 32) smv += kern[j] * kp[t];
        }
        double mx = smv;
#pragma unroll
        for (int m = 1; m < 32; m <<= 1) mx = fmax(mx, __shfl_xor(mx, m, 32));
        double e = exp(smv - mx);
        double sum = e;
#pragma unroll
        for (int m = 1; m < 32; m <<= 1) sum += __shfl_xor(sum, m, 32);
        gs[l] = e / sum;
    }
    __syncthreads();
    if (l == 0) {
        int am = 0;
        double bv = gs[0];
        for (int i = 1; i < 32; i++)
            if (gs[i] > bv) { bv = gs[i]; am = i; }
        double c = 0.;
        cs[0] = 0.;
        for (int i = 0; i < 32; i++) { c += gs[i]; cs[i + 1] = c; }
        double best = -INFINITY;
        int bs0 = 0, be0 = 0;
        const int wsz[3] = {1, 3, 5};
        for (int wi = 0; wi < 3; wi++) {
            int w = wsz[wi];
            for (int st = 0; st <= 32 - w; st++) {
                if (am >= st && am < st + w) {
                    double sc = cs[st + w] - cs[st];
                    if (sc > best) { best = sc; bs0 = st; be0 = st + w; }
                }
            }
        }
        sb[0] = bs0;
        sb[1] = be0;
    }
    __syncthreads();
    int st0 = sb[0], en0 = sb[1];
    float* o_gs = out;
    float* o_idx = out + 131072;
    float* o_st = out + 139264;
    float* o_et = out + 143360;
    float* o_mask = out + 147456;
    float* o_ok = out + 278528;
    if (l < 32) {
        o_gs[(b << 5) + l] = (float)gs[l];
        o_mask[(b << 5) + l] = (l >= st0 && l <= en0) ? 1.f : 0.f;
        o_ok[(b << 5) + l] = (float)lg[l];
    }
    if (l == 0) {
        o_idx[(b << 1)] = (float)st0;
        o_idx[(b << 1) + 1] = (float)en0;
        o_st[b] = (float)((double)st0 / 31.0);
        o_et[b] = (float)((double)en0 / 31.0);
    }
}

// ---------------------------------------------------------------------------
extern "C" void kernel_launch(void* const* d_in, const int* in_sizes, int n_in,
                              void* d_out, int out_size, void* d_ws, size_t ws_size,
                              hipStream_t stream) {
    (void)in_sizes; (void)n_in; (void)out_size;
    const float* v = (const float*)d_in[0];
    const float* qa = (const float*)d_in[1];
    const float* vp_g = (const float*)d_in[2];
    const float* vp_b = (const float*)d_in[3];
    const float* vp_W = (const float*)d_in[4];
    const float* vp_bias = (const float*)d_in[5];
    const float* qp_g = (const float*)d_in[6];
    const float* qp_b = (const float*)d_in[7];
    const float* qp_W = (const float*)d_in[8];
    const float* qp_bias = (const float*)d_in[9];
    const float* gr_g = (const float*)d_in[10];
    const float* gr_b = (const float*)d_in[11];
    const float* gr_W1 = (const float*)d_in[12];
    const float* gr_b1 = (const float*)d_in[13];
    const float* gr_W2 = (const float*)d_in[14];
    const float* gr_b2 = (const float*)d_in[15];
    const float* sigma = (const float*)d_in[16];
    float* out = (float*)d_out;

    // workspace layout (doubles)
    double* p = (double*)d_ws;
    double* qa_mean = p; p += BSZ;
    double* qa_rstd = p; p += BSZ;
    double* qa2 = p; p += (size_t)BSZ * DD;
    double* logits = p; p += (size_t)BSZ * LL;

    size_t fixed = (size_t)BSZ * 2 + (size_t)BSZ * DD + (size_t)BSZ * LL;
    int bpc = 1024;  // batches per chunk; shrink until scratch fits
    while (bpc > 32) {
        size_t rows = (size_t)bpc * LL;
        size_t need = fixed + rows * 4 + rows * DD;
        if (need * sizeof(double) <= ws_size) break;
        bpc >>= 1;
    }
    size_t rows = (size_t)bpc * LL;
    double* v_mean = p; p += rows;
    double* v_rstd = p; p += rows;
    double* s1 = p; p += rows;
    double* s2 = p; p += rows;
    double* v2 = p; p += rows * DD;

    // qa path (once)
    row_stats_k<<<dim3((unsigned)((BSZ * 64) / 256)), dim3(256), 0, stream>>>(
        qa, qa_mean, qa_rstd, BSZ);
    gemm_ln_gelu_k<<<dim3(BSZ / 128, DD / 64), dim3(256), 0, stream>>>(
        qa, qa_mean, qa_rstd, qp_g, qp_b, qp_W, qp_bias, qa2, DD);

    int nch = BSZ / bpc;
    for (int c = 0; c < nch; c++) {
        int rowbase = c * (int)rows;
        const float* vchunk = v + (size_t)rowbase * DD;
        row_stats_k<<<dim3((unsigned)((rows * 64) / 256)), dim3(256), 0, stream>>>(
            vchunk, v_mean, v_rstd, (int)rows);
        gemm_ln_gelu_k<<<dim3((unsigned)(rows / 128), DD / 64), dim3(256), 0, stream>>>(
            vchunk, v_mean, v_rstd, vp_g, vp_b, vp_W, vp_bias, v2, DD);
        gate_stats_k<<<dim3((unsigned)((rows * 64) / 256)), dim3(256), 0, stream>>>(
            v2, qa2, s1, s2, logits, gr_b2, rowbase, (int)rows);
        gemm_h_logits_k<<<dim3((unsigned)(rows / 128), HH / 64), dim3(256), 0, stream>>>(
            v2, s1, s2, gr_g, gr_b, gr_W1, gr_b1, gr_W2, logits + rowbase);
    }
    finalize_k<<<dim3(BSZ), dim3(64), 0, stream>>>(logits, sigma, out);
}